// Round 1
// baseline (26.111 us; speedup 1.0000x reference)
//
#include <hip/hip_runtime.h>

#define BLOCK 256

// per-profile targets (5 entries) and config multipliers (4 entries)
__device__ __constant__ float c_target_delay[5] = {2.0f, 1.0f, 0.5f, 5.0f, 3.0f};
__device__ __constant__ float c_target_pad[5]   = {0.08f, 0.12f, 0.05f, 0.15f, 0.10f};
__device__ __constant__ float c_config_mult[4]  = {1.0f, 1.3f, 1.6f, 2.0f};

// One block per row. Each thread handles 8 contiguous elements.
__global__ __launch_bounds__(BLOCK) void row_loss_kernel(
    const int*   __restrict__ sizes,      // [B,S] int32
    const float* __restrict__ delays,     // [B,S] f32
    const int*   __restrict__ dirs,       // [B,S] int32
    const float* __restrict__ delay_ms,   // [B]
    const float* __restrict__ pad_norm,   // [B]
    const float* __restrict__ conf,       // [B]
    const int*   __restrict__ pids,       // [B]
    float*       __restrict__ row_out,    // [B] per-row contribution to total
    int S, float invB)
{
    const int r   = blockIdx.x;
    const int tid = threadIdx.x;
    const int per = 8;                      // S == BLOCK*8 == 2048
    const long long rowoff = (long long)r * (long long)S;
    const int base = tid * per;

    const int*   srow = sizes  + rowoff;
    const float* drow = delays + rowoff;
    const int*   grow = dirs   + rowoff;

    const float pad = pad_norm[r];
    const float dly = delay_ms[r];

    // Vector loads: 8 elems = two 16B loads each, 32B-aligned chunks.
    const int4*   sv = (const int4*)(srow + base);
    const float4* dv = (const float4*)(drow + base);
    const int4*   gv = (const int4*)(grow + base);
    int4   s0 = sv[0], s1 = sv[1];
    float4 d0 = dv[0], d1 = dv[1];
    int4   g0 = gv[0], g1 = gv[1];

    float sz[8] = {(float)s0.x, (float)s0.y, (float)s0.z, (float)s0.w,
                   (float)s1.x, (float)s1.y, (float)s1.z, (float)s1.w};
    float dl[8] = {d0.x, d0.y, d0.z, d0.w, d1.x, d1.y, d1.z, d1.w};
    float dr[8] = {(float)g0.x, (float)g0.y, (float)g0.z, (float)g0.w,
                   (float)g1.x, (float)g1.y, (float)g1.z, (float)g1.w};

    // prev of this thread's first element
    float psz, pdr;
    if (base == 0) {
        psz = -1.0f; pdr = -1.0f;
    } else {
        psz = (float)srow[base - 1];
        pdr = (float)grow[base - 1];
    }

    // last-packet morphing (only the very last element of the row)
    if (base + per == S) {
        sz[7] = fminf(sz[7] + pad * 1500.0f, 1500.0f);
        dl[7] = dl[7] + dly;
    }

    float sum = 0.0f;
    #pragma unroll
    for (int j = 0; j < 8; ++j) {
        float inc = 0.0f;
        inc += (sz[j] > 1400.0f)             ? 0.6f : 0.0f;
        inc += (dl[j] < 0.05f)               ? 0.4f : 0.0f;
        inc += (fabsf(sz[j] - psz) < 0.5f)   ? 0.2f : 0.0f;
        inc += (dr[j] != pdr)                ? 0.1f : 0.0f;
        sum += inc;
        psz = sz[j];
        pdr = dr[j];
    }

    // wave (64-lane) reduce, then cross-wave via LDS
    #pragma unroll
    for (int off = 32; off > 0; off >>= 1)
        sum += __shfl_down(sum, off, 64);

    __shared__ float wsum[BLOCK / 64];
    if ((tid & 63) == 0) wsum[tid >> 6] = sum;
    __syncthreads();

    if (tid == 0) {
        float tot = 0.0f;
        #pragma unroll
        for (int w = 0; w < BLOCK / 64; ++w) tot += wsum[w];

        const int pid = pids[r];
        const float mult = c_config_mult[pid & 3];
        const float score = tot * (100.0f / (float)S) * mult;

        float v = 0.0f;
        // DPI_W * relu(score-15)/30, folded per-row
        v += (2.0f / 30.0f) * fmaxf(score - 15.0f, 0.0f);
        // SIM_W * (|delay - TD| + |pad - TP|)
        v += 0.5f * (fabsf(dly - c_target_delay[pid]) + fabsf(pad - c_target_pad[pid]));
        // EFF_W * (relu(delay-20)/20 + relu(pad-0.3))
        v += (0.3f / 20.0f) * fmaxf(dly - 20.0f, 0.0f);
        v += 0.3f * fmaxf(pad - 0.3f, 0.0f);
        // CONF_W * (conf - evasion)^2
        const float ev = (score < 30.0f) ? 1.0f : 0.0f;
        const float c  = conf[r] - ev;
        v += 0.2f * c * c;

        row_out[r] = v * invB;
    }
}

__global__ __launch_bounds__(BLOCK) void reduce_kernel(
    const float* __restrict__ row, float* __restrict__ out, int B)
{
    const int tid = threadIdx.x;
    float s = 0.0f;
    for (int i = tid; i < B; i += BLOCK) s += row[i];

    #pragma unroll
    for (int off = 32; off > 0; off >>= 1)
        s += __shfl_down(s, off, 64);

    __shared__ float wsum[BLOCK / 64];
    if ((tid & 63) == 0) wsum[tid >> 6] = s;
    __syncthreads();

    if (tid == 0) {
        float tot = 0.0f;
        #pragma unroll
        for (int w = 0; w < BLOCK / 64; ++w) tot += wsum[w];
        out[0] = tot;
    }
}

extern "C" void kernel_launch(void* const* d_in, const int* in_sizes, int n_in,
                              void* d_out, int out_size, void* d_ws, size_t ws_size,
                              hipStream_t stream) {
    const int*   sizes    = (const int*)  d_in[0];
    const float* delays   = (const float*)d_in[1];
    const int*   dirs     = (const int*)  d_in[2];
    const float* delay_ms = (const float*)d_in[3];
    const float* pad_norm = (const float*)d_in[4];
    const float* conf     = (const float*)d_in[5];
    const int*   pids     = (const int*)  d_in[6];
    float* out = (float*)d_out;

    const int B = in_sizes[3];                 // 4096
    const int S = in_sizes[0] / B;             // 2048

    float* row_ws = (float*)d_ws;              // B floats of scratch

    row_loss_kernel<<<B, BLOCK, 0, stream>>>(
        sizes, delays, dirs, delay_ms, pad_norm, conf, pids,
        row_ws, S, 1.0f / (float)B);

    reduce_kernel<<<1, BLOCK, 0, stream>>>(row_ws, out, B);
}